// Round 11
// baseline (425.972 us; speedup 1.0000x reference)
//
#include <hip/hip_runtime.h>

#define N_IN 600000
#define KK 4
#define C_IN 64
#define C_OUT 32
#define NTOT (KK*N_IN)
#define BN_EPS 1e-5f

typedef __attribute__((ext_vector_type(8))) short short8b;   // 8 bf16 (4 VGPRs)
typedef __attribute__((ext_vector_type(4))) float f32x4;     // MFMA C/D

// ws float layout:
// [0,4096)      G (64x64 Gram, final)
// [4096,4160)   s (colsum, final)
// [4160,4192)   scale[32]
// [4192,4224)   bias[32]
// [4224,8320)   W bf16 fragments (1024 uint4 = 16KB)
// [8320, +512*4160)   per-block gram partials
// [WS_INV, +NTOT)     inverse permutation (int)
// [WS_XBF, +N_IN*32)  x in bf16 row-major (uint4 x 8 per row) -- optional
#define WS_G 0
#define WS_S 4096
#define WS_SCALE 4160
#define WS_BIAS 4192
#define WS_WFRAG 4224
#define WS_PART 8320
#define PART_STRIDE 4160
#define NBA 512
#define WS_INV (WS_PART + NBA * PART_STRIDE)
#define WS_XBF (WS_INV + NTOT)

__device__ __forceinline__ unsigned short f2bf(float f) {
    unsigned int u = __float_as_uint(f);
    u += 0x7fffu + ((u >> 16) & 1u);   // RNE
    return (unsigned short)(u >> 16);
}

union FragU { uint4 u; short8b s; unsigned int w[4]; };

// ---------------- Pass A: Gram G = X^T X + colsums via MFMA -----------------
// Optionally folds: (a) inverse-permutation build (random 4B scatter hides
// under the HBM-bound loop), (b) bf16 row-major copy of x (the values are
// already converted for the MFMA staging; +77MB sequential writes).
#define GPADC 68
__global__ __launch_bounds__(256) void k_gram(const float* __restrict__ x,
                                              const int* __restrict__ oidx,
                                              int* __restrict__ inv,
                                              uint4* __restrict__ xbf,
                                              float* __restrict__ ws, int nblk) {
    __shared__ unsigned int sm[32 * GPADC];  // 32 row-pairs x 64 packed cols (+pad)
    const int t = threadIdx.x, wv = t >> 6, l = t & 63;
    const int il = l & 15, g = l >> 4;
    const int chunk = t & 7, r0 = t >> 3;

    if (inv) {  // folded k_binv: bijective scatter inv[oidx[j]] = j
        const uint4* src = (const uint4*)oidx;
        const int nq = NTOT / 4;  // 600000
        for (int q = blockIdx.x * 256 + t; q < nq; q += nblk * 256) {
            const uint4 v = src[q];
            const int j = q * 4;
            inv[v.x] = j; inv[v.y] = j + 1; inv[v.z] = j + 2; inv[v.w] = j + 3;
        }
    }

    FragU ones;
    ones.u = make_uint4(0x3f803f80u, 0x3f803f80u, 0x3f803f80u, 0x3f803f80u);

    f32x4 acc[4];
    f32x4 accs = (f32x4){0.f, 0.f, 0.f, 0.f};
#pragma unroll
    for (int j = 0; j < 4; ++j) acc[j] = (f32x4){0.f, 0.f, 0.f, 0.f};

    const int ntiles = N_IN / 64;  // 9375
    for (int tile = blockIdx.x; tile < ntiles; tile += nblk) {
        const float* base = x + (size_t)tile * 4096;
        const float4* pa = (const float4*)(base + (2 * r0) * 64 + chunk * 8);
        const float4* pb = (const float4*)(base + (2 * r0 + 1) * 64 + chunk * 8);
        const float4 a0 = pa[0], a1 = pa[1];
        const float4 b0 = pb[0], b1 = pb[1];
        unsigned int ha[8], hb[8];
        ha[0] = f2bf(a0.x); ha[1] = f2bf(a0.y); ha[2] = f2bf(a0.z); ha[3] = f2bf(a0.w);
        ha[4] = f2bf(a1.x); ha[5] = f2bf(a1.y); ha[6] = f2bf(a1.z); ha[7] = f2bf(a1.w);
        hb[0] = f2bf(b0.x); hb[1] = f2bf(b0.y); hb[2] = f2bf(b0.z); hb[3] = f2bf(b0.w);
        hb[4] = f2bf(b1.x); hb[5] = f2bf(b1.y); hb[6] = f2bf(b1.z); hb[7] = f2bf(b1.w);
        if (xbf) {  // row-major bf16 copy (consecutive-column pairs = A-frag dwords)
            xbf[(size_t)(tile * 64 + 2 * r0) * 8 + chunk] =
                make_uint4(ha[0] | (ha[1] << 16), ha[2] | (ha[3] << 16),
                           ha[4] | (ha[5] << 16), ha[6] | (ha[7] << 16));
            xbf[(size_t)(tile * 64 + 2 * r0 + 1) * 8 + chunk] =
                make_uint4(hb[0] | (hb[1] << 16), hb[2] | (hb[3] << 16),
                           hb[4] | (hb[5] << 16), hb[6] | (hb[7] << 16));
        }
        __syncthreads();  // previous tile's readers done
        unsigned int* dst = sm + r0 * GPADC + chunk * 8;
        *(uint4*)dst = make_uint4(ha[0] | (hb[0] << 16), ha[1] | (hb[1] << 16),
                                  ha[2] | (hb[2] << 16), ha[3] | (hb[3] << 16));
        *(uint4*)(dst + 4) = make_uint4(ha[4] | (hb[4] << 16), ha[5] | (hb[5] << 16),
                                        ha[6] | (hb[6] << 16), ha[7] | (hb[7] << 16));
        __syncthreads();
#pragma unroll
        for (int s = 0; s < 2; ++s) {
            short8b fr[4];
#pragma unroll
            for (int c = 0; c < 4; ++c) {
                FragU fu;
#pragma unroll
                for (int h = 0; h < 4; ++h)
                    fu.w[h] = sm[(s * 16 + g * 4 + h) * GPADC + c * 16 + il];
                fr[c] = fu.s;
            }
#pragma unroll
            for (int tj = 0; tj < 4; ++tj)
                acc[tj] = __builtin_amdgcn_mfma_f32_16x16x32_bf16(fr[wv], fr[tj], acc[tj], 0, 0, 0);
            accs = __builtin_amdgcn_mfma_f32_16x16x32_bf16(ones.s, fr[wv], accs, 0, 0, 0);
        }
    }
    float* part = ws + WS_PART + (size_t)blockIdx.x * PART_STRIDE;
#pragma unroll
    for (int tj = 0; tj < 4; ++tj)
#pragma unroll
        for (int q = 0; q < 4; ++q)
            part[(wv * 16 + g * 4 + q) * 64 + tj * 16 + il] = acc[tj][q];
    if (g == 0) part[4096 + wv * 16 + il] = accs[0];
}

// ---------------- Reduce partials: one wave per element ---------------------
__global__ __launch_bounds__(256) void k_reduce(float* __restrict__ ws, int nba) {
    const int g = blockIdx.x * 4 + (threadIdx.x >> 6);  // grid 1040 -> [0,4160)
    const int lane = threadIdx.x & 63;
    const float* p = ws + WS_PART + g;
    float s = 0.f;
    for (int b = lane; b < nba; b += 64) s += p[(size_t)b * PART_STRIDE];
#pragma unroll
    for (int m = 1; m < 64; m <<= 1) s += __shfl_xor(s, m, 64);
    if (lane == 0) ws[g] = s;
}

// ---------------- Finalize BN stats + pack W fragments ----------------------
__global__ __launch_bounds__(256) void k_finalize(const float* __restrict__ w,
                                                  const float* __restrict__ gamma,
                                                  const float* __restrict__ beta,
                                                  float* __restrict__ ws) {
    __shared__ float Gs[4096];
    __shared__ float ssum[64];
    __shared__ float red1[256], red2[256];
    const int t = threadIdx.x;

    // folded k_prepw: pack W into MFMA B-fragment layout (bf16)
    {
        uint4* dst = (uint4*)(ws + WS_WFRAG);
#pragma unroll
        for (int ii = 0; ii < 4; ++ii) {
            const int tt = ii * 256 + t;  // 0..1023
            const int l = tt & 63;
            const int s = (tt >> 6) & 1;
            const int c = tt >> 7;
            const int col = c * 16 + (l & 15);
            const int kk = col >> 5, o = col & 31;
            unsigned int pk[4];
#pragma unroll
            for (int jj = 0; jj < 4; ++jj) {
                const int k0 = s * 32 + ((l >> 4) << 3) + jj * 2;
                unsigned int b0 = f2bf(w[(kk * 64 + k0) * 32 + o]);
                unsigned int b1 = f2bf(w[(kk * 64 + k0 + 1) * 32 + o]);
                pk[jj] = b0 | (b1 << 16);
            }
            dst[tt] = make_uint4(pk[0], pk[1], pk[2], pk[3]);
        }
    }

    for (int i = t; i < 4096; i += 256) Gs[i] = ws[i];
    if (t < 64) ssum[t] = ws[WS_S + t];
    __syncthreads();
    const int sub = t >> 7;
    const int k = (t >> 5) & 3;
    const int o = t & 31;
    float wc[64];
#pragma unroll
    for (int i = 0; i < 64; ++i) wc[i] = w[(k * 64 + i) * 32 + o];
    float m1 = 0.f, m2 = 0.f;
    for (int ii = 0; ii < 32; ++ii) {
        int i = sub * 32 + ii;
        m1 = fmaf(ssum[i], wc[i], m1);
        float ti = 0.f;
#pragma unroll
        for (int j = 0; j < 64; ++j) ti = fmaf(Gs[i * 64 + j], wc[j], ti);
        m2 = fmaf(wc[i], ti, m2);
    }
    red1[t] = m1;
    red2[t] = m2;
    __syncthreads();
    if (t < 32) {
        float s1 = 0.f, s2 = 0.f;
#pragma unroll
        for (int q = 0; q < 8; ++q) {
            int idx = (q & 3) * 32 + (q >> 2) * 128 + t;
            s1 += red1[idx];
            s2 += red2[idx];
        }
        float inv = 1.f / (float)NTOT;
        float mean = s1 * inv;
        float var = s2 * inv - mean * mean;
        float rstd = rsqrtf(var + BN_EPS);
        float sc = gamma[t] * rstd;
        ws[WS_SCALE + t] = sc;
        ws[WS_BIAS + t] = beta[t] - mean * sc;
    }
}

// ---------------- Main (inverse): bf16 gather + MFMA + select + seq store ---
// Gathers come from the 77MB bf16 copy (L3-resident); the gathered uint4 IS
// the A-fragment (zero repack). Plain stores (NT proved harmful, R10).
__global__ __launch_bounds__(256, 4) void k_minv(const uint4* __restrict__ xb,
                                                 const int* __restrict__ inv,
                                                 const float* __restrict__ ws,
                                                 float* __restrict__ out) {
    __shared__ float ldsT[4][16 * 32];  // per-wave 16 rows x 32 dwords, swizzled
    const int t = threadIdx.x, wv = t >> 6, l = t & 63;
    const int il = l & 15, g = l >> 4;

    const float sc0 = ws[WS_SCALE + il], sc1 = ws[WS_SCALE + 16 + il];
    const float bs0 = ws[WS_BIAS + il], bs1 = ws[WS_BIAS + 16 + il];

    const short8b* wfs = (const short8b*)(ws + WS_WFRAG);
    short8b bwf[16];
#pragma unroll
    for (int f = 0; f < 16; ++f) bwf[f] = wfs[f * 64 + l];

    float* myT = ldsT[wv];
    const int wgid = blockIdx.x * 4 + wv;   // 0..9999
    const int base0 = wgid * 240;           // 15 tiles x 16 rows

    // prologue: tile 0's src + k, tile 1's inv value
    int j0 = inv[base0 + il];
    int k_cur = (j0 >= N_IN) + (j0 >= 2 * N_IN) + (j0 >= 3 * N_IN);
    int i_cur = j0 - k_cur * N_IN;
    uint4 cur0 = xb[(size_t)i_cur * 8 + g];
    uint4 cur1 = xb[(size_t)i_cur * 8 + 4 + g];
    int j1 = inv[base0 + 16 + il];

#pragma unroll 1
    for (int it = 0; it < 15; ++it) {
        const int base = base0 + it * 16;
        // inv prefetch for tile it+2
        int j2 = j1;
        if (it < 13) j2 = inv[base + 32 + il];
        // decompose tile it+1's source, issue its gather early
        int k_nxt = (j1 >= N_IN) + (j1 >= 2 * N_IN) + (j1 >= 3 * N_IN);
        int i_nxt = j1 - k_nxt * N_IN;
        uint4 nx0 = cur0, nx1 = cur1;
        if (it < 14) {
            nx0 = xb[(size_t)i_nxt * 8 + g];
            nx1 = xb[(size_t)i_nxt * 8 + 4 + g];
        }

        // A fragments = the gathered dwords, directly
        FragU af0, af1;
        af0.u = cur0;
        af1.u = cur1;

        f32x4 acc[8];
#pragma unroll
        for (int c = 0; c < 8; ++c) acc[c] = (f32x4){0.f, 0.f, 0.f, 0.f};
#pragma unroll
        for (int c = 0; c < 8; ++c)
            acc[c] = __builtin_amdgcn_mfma_f32_16x16x32_bf16(af0.s, bwf[c * 2 + 0], acc[c], 0, 0, 0);
#pragma unroll
        for (int c = 0; c < 8; ++c)
            acc[c] = __builtin_amdgcn_mfma_f32_16x16x32_bf16(af1.s, bwf[c * 2 + 1], acc[c], 0, 0, 0);

        // per-row k-slice select + BN + ReLU -> swizzled LDS
#pragma unroll
        for (int q = 0; q < 4; ++q) {
            const int r = g * 4 + q;
            const int kq = __shfl(k_cur, r, 64);
            const float lo = (kq == 0) ? acc[0][q] : (kq == 1) ? acc[2][q] : (kq == 2) ? acc[4][q] : acc[6][q];
            const float hi = (kq == 0) ? acc[1][q] : (kq == 1) ? acc[3][q] : (kq == 2) ? acc[5][q] : acc[7][q];
            const float vlo = fmaxf(0.f, fmaf(lo, sc0, bs0));
            const float vhi = fmaxf(0.f, fmaf(hi, sc1, bs1));
            const int ccl = il >> 2, wd = il & 3, rx = r & 7;
            myT[r * 32 + (((ccl ^ rx) << 2) | wd)] = vlo;
            myT[r * 32 + ((((ccl + 4) ^ rx) << 2) | wd)] = vhi;
        }
        // read back + sequential store (2KB contiguous per wave)
        {
            const int r = l >> 2;
            const int cbase = (l & 3) * 2;
            const int cpc0 = (cbase + 0) ^ (r & 7);
            const int cpc1 = (cbase + 1) ^ (r & 7);
            const float4 v0 = *(const float4*)(myT + r * 32 + (cpc0 << 2));
            const float4 v1 = *(const float4*)(myT + r * 32 + (cpc1 << 2));
            float* op = out + (size_t)base * 32 + l * 8;
            *(float4*)op = v0;
            *(float4*)(op + 4) = v1;
        }

        cur0 = nx0; cur1 = nx1;
        k_cur = k_nxt;
        j1 = j2;
    }
}

// ---------------- Fallback main (forward scatter, R8-proven) ----------------
__global__ __launch_bounds__(256, 4) void k_main(const float* __restrict__ x,
                                                 const int* __restrict__ oidx,
                                                 const float* __restrict__ ws,
                                                 float* __restrict__ out) {
    __shared__ float ldsD[4][64 * 32];
    __shared__ int ldsO[4][64];
    const int t = threadIdx.x, wv = t >> 6, l = t & 63;
    const int il = l & 15, g = l >> 4;
    const int c8 = l & 7, g8 = l >> 3;

    const float sc0 = ws[WS_SCALE + il], sc1 = ws[WS_SCALE + 16 + il];
    const float bs0 = ws[WS_BIAS + il], bs1 = ws[WS_BIAS + 16 + il];
    const short8b* wfs = (const short8b*)(ws + WS_WFRAG);

    float* myD = ldsD[wv];
    int* myO = ldsO[wv];

    const int wgid = blockIdx.x * 4 + wv;  // 0..7499
    int rowbase = wgid * 80;               // 5 tiles x 16 rows

    float4 cur0, cur1, cur2, cur3;
    {
        const float4* ap = (const float4*)(x + (size_t)(rowbase + il) * 64 + g * 8);
        cur0 = ap[0]; cur1 = ap[1]; cur2 = ap[8]; cur3 = ap[9];
    }
    int orow_cur = oidx[g * N_IN + rowbase + il];

#pragma unroll
    for (int it = 0; it < 5; ++it) {
        myO[l] = orow_cur;

        FragU af0, af1;
        af0.w[0] = (unsigned)f2bf(cur0.x) | ((unsigned)f2bf(cur0.y) << 16);
        af0.w[1] = (unsigned)f2bf(cur0.z) | ((unsigned)f2bf(cur0.w) << 16);
        af0.w[2] = (unsigned)f2bf(cur1.x) | ((unsigned)f2bf(cur1.y) << 16);
        af0.w[3] = (unsigned)f2bf(cur1.z) | ((unsigned)f2bf(cur1.w) << 16);
        af1.w[0] = (unsigned)f2bf(cur2.x) | ((unsigned)f2bf(cur2.y) << 16);
        af1.w[1] = (unsigned)f2bf(cur2.z) | ((unsigned)f2bf(cur2.w) << 16);
        af1.w[2] = (unsigned)f2bf(cur3.x) | ((unsigned)f2bf(cur3.y) << 16);
        af1.w[3] = (unsigned)f2bf(cur3.z) | ((unsigned)f2bf(cur3.w) << 16);

        float4 nx0{}, nx1{}, nx2{}, nx3{};
        int orow_nxt = 0;
        if (it < 4) {
            const float4* ap = (const float4*)(x + (size_t)(rowbase + 16 + il) * 64 + g * 8);
            nx0 = ap[0]; nx1 = ap[1]; nx2 = ap[8]; nx3 = ap[9];
            orow_nxt = oidx[g * N_IN + rowbase + 16 + il];
        }

        f32x4 acc[8];
#pragma unroll
        for (int c = 0; c < 8; ++c) acc[c] = (f32x4){0.f, 0.f, 0.f, 0.f};
#pragma unroll
        for (int c = 0; c < 8; ++c)
            acc[c] = __builtin_amdgcn_mfma_f32_16x16x32_bf16(af0.s, wfs[(c * 2 + 0) * 64 + l], acc[c], 0, 0, 0);
#pragma unroll
        for (int c = 0; c < 8; ++c)
            acc[c] = __builtin_amdgcn_mfma_f32_16x16x32_bf16(af1.s, wfs[(c * 2 + 1) * 64 + l], acc[c], 0, 0, 0);

#pragma unroll
        for (int c = 0; c < 8; ++c) {
            const float sc = (c & 1) ? sc1 : sc0;
            const float bs = (c & 1) ? bs1 : bs0;
            const int ch = (c & 1) * 16 + il;
            const int cc = ch >> 2, wd = ch & 3;
            const int rb = (c >> 1) * 16 + g * 4;
#pragma unroll
            for (int q = 0; q < 4; ++q) {
                const int R = rb + q;
                const float v = fmaxf(0.f, fmaf(acc[c][q], sc, bs));
                myD[R * 32 + (((cc ^ (R & 7)) << 2) | wd)] = v;
            }
        }
#pragma unroll
        for (int m = 0; m < 8; ++m) {
            const int R = m * 8 + g8;
            const float4 v = *(const float4*)(myD + R * 32 + ((c8 ^ g8) << 2));
            const int orow = myO[R];
            *(float4*)(out + (size_t)orow * 32 + c8 * 4) = v;
        }

        rowbase += 16;
        cur0 = nx0; cur1 = nx1; cur2 = nx2; cur3 = nx3;
        orow_cur = orow_nxt;
    }
}

extern "C" void kernel_launch(void* const* d_in, const int* in_sizes, int n_in,
                              void* d_out, int out_size, void* d_ws, size_t ws_size,
                              hipStream_t stream) {
    const float* x = (const float*)d_in[0];
    const float* w = (const float*)d_in[1];
    const float* gamma = (const float*)d_in[2];
    const float* beta = (const float*)d_in[3];
    const int* oidx = (const int*)d_in[4];
    float* out = (float*)d_out;
    float* ws = (float*)d_ws;

    const size_t need = ((size_t)WS_XBF + (size_t)N_IN * 32) * sizeof(float);
    const bool use_inverse = (ws_size >= need);

    if (use_inverse) {
        int* inv = (int*)(ws + WS_INV);
        uint4* xbf = (uint4*)(ws + WS_XBF);
        hipLaunchKernelGGL(k_gram, dim3(NBA), dim3(256), 0, stream, x, oidx, inv, xbf, ws, NBA);
        hipLaunchKernelGGL(k_reduce, dim3(1040), dim3(256), 0, stream, ws, NBA);
        hipLaunchKernelGGL(k_finalize, dim3(1), dim3(256), 0, stream, w, gamma, beta, ws);
        hipLaunchKernelGGL(k_minv, dim3(2500), dim3(256), 0, stream, (const uint4*)xbf, inv, ws, out);
    } else {
        hipLaunchKernelGGL(k_gram, dim3(NBA), dim3(256), 0, stream, x, oidx, (int*)nullptr,
                           (uint4*)nullptr, ws, NBA);
        hipLaunchKernelGGL(k_reduce, dim3(1040), dim3(256), 0, stream, ws, NBA);
        hipLaunchKernelGGL(k_finalize, dim3(1), dim3(256), 0, stream, w, gamma, beta, ws);
        hipLaunchKernelGGL(k_main, dim3(1875), dim3(256), 0, stream, x, oidx, ws, out);
    }
}

// Round 12
// 283.932 us; speedup vs baseline: 1.5003x; 1.5003x over previous
//
#include <hip/hip_runtime.h>

#define N_IN 600000
#define KK 4
#define C_IN 64
#define C_OUT 32
#define NTOT (KK*N_IN)
#define BN_EPS 1e-5f

typedef __attribute__((ext_vector_type(8))) short short8b;   // 8 bf16 (4 VGPRs)
typedef __attribute__((ext_vector_type(4))) float f32x4;     // MFMA C/D

// ws float layout:
// [0,4096)      G (64x64 Gram, final)
// [4096,4160)   s (colsum, final)
// [4160,4192)   scale[32]
// [4192,4224)   bias[32]
// [4224,8320)   W bf16 fragments (1024 uint4 = 16KB)
// [8320, +512*4160)   per-block gram partials
// [WS_XBF, +N_IN*16)  x in bf16 row-major (8 uint4 per row), A-frag dword order
#define WS_G 0
#define WS_S 4096
#define WS_SCALE 4160
#define WS_BIAS 4192
#define WS_WFRAG 4224
#define WS_PART 8320
#define PART_STRIDE 4160
#define NBA 512
#define WS_XBF (WS_PART + NBA * PART_STRIDE)

__device__ __forceinline__ unsigned short f2bf(float f) {
    unsigned int u = __float_as_uint(f);
    u += 0x7fffu + ((u >> 16) & 1u);   // RNE
    return (unsigned short)(u >> 16);
}

union FragU { uint4 u; short8b s; unsigned int w[4]; };

// ---------------- Pass A: Gram G = X^T X + colsums via MFMA -----------------
// Also emits the bf16 row-major copy of x (conversions are computed here
// anyway for the MFMA staging) so k_main can read half the bytes and skip
// all f2bf/pack VALU in its hot loop.
#define GPADC 68
__global__ __launch_bounds__(256) void k_gram(const float* __restrict__ x,
                                              uint4* __restrict__ xbf,
                                              float* __restrict__ ws, int nblk) {
    __shared__ unsigned int sm[32 * GPADC];  // 32 row-pairs x 64 packed cols (+pad)
    const int t = threadIdx.x, wv = t >> 6, l = t & 63;
    const int il = l & 15, g = l >> 4;
    const int chunk = t & 7, r0 = t >> 3;

    FragU ones;
    ones.u = make_uint4(0x3f803f80u, 0x3f803f80u, 0x3f803f80u, 0x3f803f80u);

    f32x4 acc[4];
    f32x4 accs = (f32x4){0.f, 0.f, 0.f, 0.f};
#pragma unroll
    for (int j = 0; j < 4; ++j) acc[j] = (f32x4){0.f, 0.f, 0.f, 0.f};

    const int ntiles = N_IN / 64;  // 9375
    for (int tile = blockIdx.x; tile < ntiles; tile += nblk) {
        const float* base = x + (size_t)tile * 4096;
        const float4* pa = (const float4*)(base + (2 * r0) * 64 + chunk * 8);
        const float4* pb = (const float4*)(base + (2 * r0 + 1) * 64 + chunk * 8);
        const float4 a0 = pa[0], a1 = pa[1];
        const float4 b0 = pb[0], b1 = pb[1];
        unsigned int ha[8], hb[8];
        ha[0] = f2bf(a0.x); ha[1] = f2bf(a0.y); ha[2] = f2bf(a0.z); ha[3] = f2bf(a0.w);
        ha[4] = f2bf(a1.x); ha[5] = f2bf(a1.y); ha[6] = f2bf(a1.z); ha[7] = f2bf(a1.w);
        hb[0] = f2bf(b0.x); hb[1] = f2bf(b0.y); hb[2] = f2bf(b0.z); hb[3] = f2bf(b0.w);
        hb[4] = f2bf(b1.x); hb[5] = f2bf(b1.y); hb[6] = f2bf(b1.z); hb[7] = f2bf(b1.w);
        if (xbf) {  // row-major bf16 copy (consecutive-column pairs = A-frag dwords)
            xbf[(size_t)(tile * 64 + 2 * r0) * 8 + chunk] =
                make_uint4(ha[0] | (ha[1] << 16), ha[2] | (ha[3] << 16),
                           ha[4] | (ha[5] << 16), ha[6] | (ha[7] << 16));
            xbf[(size_t)(tile * 64 + 2 * r0 + 1) * 8 + chunk] =
                make_uint4(hb[0] | (hb[1] << 16), hb[2] | (hb[3] << 16),
                           hb[4] | (hb[5] << 16), hb[6] | (hb[7] << 16));
        }
        __syncthreads();  // previous tile's readers done
        unsigned int* dst = sm + r0 * GPADC + chunk * 8;
        *(uint4*)dst = make_uint4(ha[0] | (hb[0] << 16), ha[1] | (hb[1] << 16),
                                  ha[2] | (hb[2] << 16), ha[3] | (hb[3] << 16));
        *(uint4*)(dst + 4) = make_uint4(ha[4] | (hb[4] << 16), ha[5] | (hb[5] << 16),
                                        ha[6] | (hb[6] << 16), ha[7] | (hb[7] << 16));
        __syncthreads();
#pragma unroll
        for (int s = 0; s < 2; ++s) {
            short8b fr[4];
#pragma unroll
            for (int c = 0; c < 4; ++c) {
                FragU fu;
#pragma unroll
                for (int h = 0; h < 4; ++h)
                    fu.w[h] = sm[(s * 16 + g * 4 + h) * GPADC + c * 16 + il];
                fr[c] = fu.s;
            }
#pragma unroll
            for (int tj = 0; tj < 4; ++tj)
                acc[tj] = __builtin_amdgcn_mfma_f32_16x16x32_bf16(fr[wv], fr[tj], acc[tj], 0, 0, 0);
            accs = __builtin_amdgcn_mfma_f32_16x16x32_bf16(ones.s, fr[wv], accs, 0, 0, 0);
        }
    }
    float* part = ws + WS_PART + (size_t)blockIdx.x * PART_STRIDE;
#pragma unroll
    for (int tj = 0; tj < 4; ++tj)
#pragma unroll
        for (int q = 0; q < 4; ++q)
            part[(wv * 16 + g * 4 + q) * 64 + tj * 16 + il] = acc[tj][q];
    if (g == 0) part[4096 + wv * 16 + il] = accs[0];
}

// ---------------- Reduce partials: one wave per element ---------------------
__global__ __launch_bounds__(256) void k_reduce(float* __restrict__ ws, int nba) {
    const int g = blockIdx.x * 4 + (threadIdx.x >> 6);  // grid 1040 -> [0,4160)
    const int lane = threadIdx.x & 63;
    const float* p = ws + WS_PART + g;
    float s = 0.f;
    for (int b = lane; b < nba; b += 64) s += p[(size_t)b * PART_STRIDE];
#pragma unroll
    for (int m = 1; m < 64; m <<= 1) s += __shfl_xor(s, m, 64);
    if (lane == 0) ws[g] = s;
}

// ---------------- Finalize BN stats + pack W fragments ----------------------
__global__ __launch_bounds__(256) void k_finalize(const float* __restrict__ w,
                                                  const float* __restrict__ gamma,
                                                  const float* __restrict__ beta,
                                                  float* __restrict__ ws) {
    __shared__ float Gs[4096];
    __shared__ float ssum[64];
    __shared__ float red1[256], red2[256];
    const int t = threadIdx.x;

    // folded k_prepw: pack W into MFMA B-fragment layout (bf16)
    {
        uint4* dst = (uint4*)(ws + WS_WFRAG);
#pragma unroll
        for (int ii = 0; ii < 4; ++ii) {
            const int tt = ii * 256 + t;  // 0..1023
            const int l = tt & 63;
            const int s = (tt >> 6) & 1;
            const int c = tt >> 7;
            const int col = c * 16 + (l & 15);
            const int kk = col >> 5, o = col & 31;
            unsigned int pk[4];
#pragma unroll
            for (int jj = 0; jj < 4; ++jj) {
                const int k0 = s * 32 + ((l >> 4) << 3) + jj * 2;
                unsigned int b0 = f2bf(w[(kk * 64 + k0) * 32 + o]);
                unsigned int b1 = f2bf(w[(kk * 64 + k0 + 1) * 32 + o]);
                pk[jj] = b0 | (b1 << 16);
            }
            dst[tt] = make_uint4(pk[0], pk[1], pk[2], pk[3]);
        }
    }

    for (int i = t; i < 4096; i += 256) Gs[i] = ws[i];
    if (t < 64) ssum[t] = ws[WS_S + t];
    __syncthreads();
    const int sub = t >> 7;
    const int k = (t >> 5) & 3;
    const int o = t & 31;
    float wc[64];
#pragma unroll
    for (int i = 0; i < 64; ++i) wc[i] = w[(k * 64 + i) * 32 + o];
    float m1 = 0.f, m2 = 0.f;
    for (int ii = 0; ii < 32; ++ii) {
        int i = sub * 32 + ii;
        m1 = fmaf(ssum[i], wc[i], m1);
        float ti = 0.f;
#pragma unroll
        for (int j = 0; j < 64; ++j) ti = fmaf(Gs[i * 64 + j], wc[j], ti);
        m2 = fmaf(wc[i], ti, m2);
    }
    red1[t] = m1;
    red2[t] = m2;
    __syncthreads();
    if (t < 32) {
        float s1 = 0.f, s2 = 0.f;
#pragma unroll
        for (int q = 0; q < 8; ++q) {
            int idx = (q & 3) * 32 + (q >> 2) * 128 + t;
            s1 += red1[idx];
            s2 += red2[idx];
        }
        float inv = 1.f / (float)NTOT;
        float mean = s1 * inv;
        float var = s2 * inv - mean * mean;
        float rstd = rsqrtf(var + BN_EPS);
        float sc = gamma[t] * rstd;
        ws[WS_SCALE + t] = sc;
        ws[WS_BIAS + t] = beta[t] - mean * sc;
    }
}

// ---------------- Main: bf16-read MFMA GEMM + BN + ReLU + coalesced scatter -
// Forward order (proven best, R8). Reads the bf16 copy: 2 uint4 per lane per
// tile (A-fragments directly, zero repack VALU). Epilogue: chunk-XOR-swizzled
// LDS transpose + 8-lanes-per-row stores (each store = 8 FULL 128B lines).
// Grid 1875 x 4 waves x 5 tiles = 37500 tiles.
__global__ __launch_bounds__(256, 4) void k_main_bf(const uint4* __restrict__ xb,
                                                    const int* __restrict__ oidx,
                                                    const float* __restrict__ ws,
                                                    float* __restrict__ out) {
    __shared__ float ldsD[4][64 * 32];
    __shared__ int ldsO[4][64];
    const int t = threadIdx.x, wv = t >> 6, l = t & 63;
    const int il = l & 15, g = l >> 4;
    const int c8 = l & 7, g8 = l >> 3;

    const float sc0 = ws[WS_SCALE + il], sc1 = ws[WS_SCALE + 16 + il];
    const float bs0 = ws[WS_BIAS + il], bs1 = ws[WS_BIAS + 16 + il];
    const short8b* wfs = (const short8b*)(ws + WS_WFRAG);

    float* myD = ldsD[wv];
    int* myO = ldsO[wv];

    const int wgid = blockIdx.x * 4 + wv;  // 0..7499
    int rowbase = wgid * 80;               // 5 tiles x 16 rows

    // prefetch tile 0 (A-fragments directly)
    uint4 cur0 = xb[(size_t)(rowbase + il) * 8 + g];
    uint4 cur1 = xb[(size_t)(rowbase + il) * 8 + 4 + g];
    int orow_cur = oidx[g * N_IN + rowbase + il];

#pragma unroll
    for (int it = 0; it < 5; ++it) {
        myO[l] = orow_cur;

        FragU af0, af1;
        af0.u = cur0;
        af1.u = cur1;

        // prefetch next tile (overlaps MFMA + epilogue)
        uint4 nx0 = cur0, nx1 = cur1;
        int orow_nxt = 0;
        if (it < 4) {
            nx0 = xb[(size_t)(rowbase + 16 + il) * 8 + g];
            nx1 = xb[(size_t)(rowbase + 16 + il) * 8 + 4 + g];
            orow_nxt = oidx[g * N_IN + rowbase + 16 + il];
        }

        f32x4 acc[8];
#pragma unroll
        for (int c = 0; c < 8; ++c) acc[c] = (f32x4){0.f, 0.f, 0.f, 0.f};
#pragma unroll
        for (int c = 0; c < 8; ++c)
            acc[c] = __builtin_amdgcn_mfma_f32_16x16x32_bf16(af0.s, wfs[(c * 2 + 0) * 64 + l], acc[c], 0, 0, 0);
#pragma unroll
        for (int c = 0; c < 8; ++c)
            acc[c] = __builtin_amdgcn_mfma_f32_16x16x32_bf16(af1.s, wfs[(c * 2 + 1) * 64 + l], acc[c], 0, 0, 0);

        // BN + ReLU -> swizzled LDS: phys dword = R*32 + ((cc ^ (R&7))<<2) + wd
#pragma unroll
        for (int c = 0; c < 8; ++c) {
            const float sc = (c & 1) ? sc1 : sc0;
            const float bs = (c & 1) ? bs1 : bs0;
            const int ch = (c & 1) * 16 + il;
            const int cc = ch >> 2, wd = ch & 3;
            const int rb = (c >> 1) * 16 + g * 4;
#pragma unroll
            for (int q = 0; q < 4; ++q) {
                const int R = rb + q;
                const float v = fmaxf(0.f, fmaf(acc[c][q], sc, bs));
                myD[R * 32 + (((cc ^ (R & 7)) << 2) | wd)] = v;
            }
        }
        // stores: lane group g8 owns row R=m*8+g8, chunk c8; R&7==g8 always
#pragma unroll
        for (int m = 0; m < 8; ++m) {
            const int R = m * 8 + g8;
            const float4 v = *(const float4*)(myD + R * 32 + ((c8 ^ g8) << 2));
            const int orow = myO[R];
            *(float4*)(out + (size_t)orow * 32 + c8 * 4) = v;
        }

        rowbase += 16;
        cur0 = nx0; cur1 = nx1;
        orow_cur = orow_nxt;
    }
}

// ---------------- Fallback main (fp32 reads, R8-proven) ---------------------
__global__ __launch_bounds__(256, 4) void k_main_f32(const float* __restrict__ x,
                                                     const int* __restrict__ oidx,
                                                     const float* __restrict__ ws,
                                                     float* __restrict__ out) {
    __shared__ float ldsD[4][64 * 32];
    __shared__ int ldsO[4][64];
    const int t = threadIdx.x, wv = t >> 6, l = t & 63;
    const int il = l & 15, g = l >> 4;
    const int c8 = l & 7, g8 = l >> 3;

    const float sc0 = ws[WS_SCALE + il], sc1 = ws[WS_SCALE + 16 + il];
    const float bs0 = ws[WS_BIAS + il], bs1 = ws[WS_BIAS + 16 + il];
    const short8b* wfs = (const short8b*)(ws + WS_WFRAG);

    float* myD = ldsD[wv];
    int* myO = ldsO[wv];

    const int wgid = blockIdx.x * 4 + wv;
    int rowbase = wgid * 80;

    float4 cur0, cur1, cur2, cur3;
    {
        const float4* ap = (const float4*)(x + (size_t)(rowbase + il) * 64 + g * 8);
        cur0 = ap[0]; cur1 = ap[1]; cur2 = ap[8]; cur3 = ap[9];
    }
    int orow_cur = oidx[g * N_IN + rowbase + il];

#pragma unroll
    for (int it = 0; it < 5; ++it) {
        myO[l] = orow_cur;

        FragU af0, af1;
        af0.w[0] = (unsigned)f2bf(cur0.x) | ((unsigned)f2bf(cur0.y) << 16);
        af0.w[1] = (unsigned)f2bf(cur0.z) | ((unsigned)f2bf(cur0.w) << 16);
        af0.w[2] = (unsigned)f2bf(cur1.x) | ((unsigned)f2bf(cur1.y) << 16);
        af0.w[3] = (unsigned)f2bf(cur1.z) | ((unsigned)f2bf(cur1.w) << 16);
        af1.w[0] = (unsigned)f2bf(cur2.x) | ((unsigned)f2bf(cur2.y) << 16);
        af1.w[1] = (unsigned)f2bf(cur2.z) | ((unsigned)f2bf(cur2.w) << 16);
        af1.w[2] = (unsigned)f2bf(cur3.x) | ((unsigned)f2bf(cur3.y) << 16);
        af1.w[3] = (unsigned)f2bf(cur3.z) | ((unsigned)f2bf(cur3.w) << 16);

        float4 nx0{}, nx1{}, nx2{}, nx3{};
        int orow_nxt = 0;
        if (it < 4) {
            const float4* ap = (const float4*)(x + (size_t)(rowbase + 16 + il) * 64 + g * 8);
            nx0 = ap[0]; nx1 = ap[1]; nx2 = ap[8]; nx3 = ap[9];
            orow_nxt = oidx[g * N_IN + rowbase + 16 + il];
        }

        f32x4 acc[8];
#pragma unroll
        for (int c = 0; c < 8; ++c) acc[c] = (f32x4){0.f, 0.f, 0.f, 0.f};
#pragma unroll
        for (int c = 0; c < 8; ++c)
            acc[c] = __builtin_amdgcn_mfma_f32_16x16x32_bf16(af0.s, wfs[(c * 2 + 0) * 64 + l], acc[c], 0, 0, 0);
#pragma unroll
        for (int c = 0; c < 8; ++c)
            acc[c] = __builtin_amdgcn_mfma_f32_16x16x32_bf16(af1.s, wfs[(c * 2 + 1) * 64 + l], acc[c], 0, 0, 0);

#pragma unroll
        for (int c = 0; c < 8; ++c) {
            const float sc = (c & 1) ? sc1 : sc0;
            const float bs = (c & 1) ? bs1 : bs0;
            const int ch = (c & 1) * 16 + il;
            const int cc = ch >> 2, wd = ch & 3;
            const int rb = (c >> 1) * 16 + g * 4;
#pragma unroll
            for (int q = 0; q < 4; ++q) {
                const int R = rb + q;
                const float v = fmaxf(0.f, fmaf(acc[c][q], sc, bs));
                myD[R * 32 + (((cc ^ (R & 7)) << 2) | wd)] = v;
            }
        }
#pragma unroll
        for (int m = 0; m < 8; ++m) {
            const int R = m * 8 + g8;
            const float4 v = *(const float4*)(myD + R * 32 + ((c8 ^ g8) << 2));
            const int orow = myO[R];
            *(float4*)(out + (size_t)orow * 32 + c8 * 4) = v;
        }

        rowbase += 16;
        cur0 = nx0; cur1 = nx1; cur2 = nx2; cur3 = nx3;
        orow_cur = orow_nxt;
    }
}

extern "C" void kernel_launch(void* const* d_in, const int* in_sizes, int n_in,
                              void* d_out, int out_size, void* d_ws, size_t ws_size,
                              hipStream_t stream) {
    const float* x = (const float*)d_in[0];
    const float* w = (const float*)d_in[1];
    const float* gamma = (const float*)d_in[2];
    const float* beta = (const float*)d_in[3];
    const int* oidx = (const int*)d_in[4];
    float* out = (float*)d_out;
    float* ws = (float*)d_ws;

    const size_t need = ((size_t)WS_XBF + (size_t)N_IN * 16) * sizeof(float);
    const bool use_bf = (ws_size >= need);
    uint4* xbf = use_bf ? (uint4*)(ws + WS_XBF) : (uint4*)nullptr;

    hipLaunchKernelGGL(k_gram, dim3(NBA), dim3(256), 0, stream, x, xbf, ws, NBA);
    hipLaunchKernelGGL(k_reduce, dim3(1040), dim3(256), 0, stream, ws, NBA);
    hipLaunchKernelGGL(k_finalize, dim3(1), dim3(256), 0, stream, w, gamma, beta, ws);
    if (use_bf) {
        hipLaunchKernelGGL(k_main_bf, dim3(1875), dim3(256), 0, stream,
                           (const uint4*)xbf, oidx, ws, out);
    } else {
        hipLaunchKernelGGL(k_main_f32, dim3(1875), dim3(256), 0, stream, x, oidx, ws, out);
    }
}

// Round 13
// 274.257 us; speedup vs baseline: 1.5532x; 1.0353x over previous
//
#include <hip/hip_runtime.h>

#define N_IN 600000
#define KK 4
#define C_IN 64
#define C_OUT 32
#define NTOT (KK*N_IN)
#define BN_EPS 1e-5f

typedef __attribute__((ext_vector_type(8))) short short8b;   // 8 bf16 (4 VGPRs)
typedef __attribute__((ext_vector_type(4))) float f32x4;     // MFMA C/D

// ws float layout:
// [0,4096)      G (64x64 Gram, final)
// [4096,4160)   s (colsum, final)
// [4160,4192)   scale[32]
// [4192,4224)   bias[32]
// [4224,8320)   W bf16 fragments (1024 uint4 = 16KB)
// [8320, +1024*4160)  per-block gram partials
#define WS_G 0
#define WS_S 4096
#define WS_SCALE 4160
#define WS_BIAS 4192
#define WS_WFRAG 4224
#define WS_PART 8320
#define PART_STRIDE 4160
#define NBA 1024

__device__ __forceinline__ unsigned short f2bf(float f) {
    unsigned int u = __float_as_uint(f);
    u += 0x7fffu + ((u >> 16) & 1u);   // RNE
    return (unsigned short)(u >> 16);
}

union FragU { uint4 u; short8b s; unsigned int w[4]; };

// ---------------- Pass A: Gram G = X^T X + colsums via MFMA -----------------
// Software-pipelined: tile t+1's global loads are issued right after the
// staging barrier and fly under tile t's MFMA phase. 1024 blocks (4/CU).
#define GPADC 68
__global__ __launch_bounds__(256) void k_gram(const float* __restrict__ x,
                                              float* __restrict__ ws, int nblk) {
    __shared__ unsigned int sm[32 * GPADC];  // 32 row-pairs x 64 packed cols (+pad)
    const int t = threadIdx.x, wv = t >> 6, l = t & 63;
    const int il = l & 15, g = l >> 4;
    const int chunk = t & 7, r0 = t >> 3;

    FragU ones;
    ones.u = make_uint4(0x3f803f80u, 0x3f803f80u, 0x3f803f80u, 0x3f803f80u);

    f32x4 acc[4];
    f32x4 accs = (f32x4){0.f, 0.f, 0.f, 0.f};
#pragma unroll
    for (int j = 0; j < 4; ++j) acc[j] = (f32x4){0.f, 0.f, 0.f, 0.f};

    const int ntiles = N_IN / 64;  // 9375
    int tile = blockIdx.x;
    float4 a0{}, a1{}, b0{}, b1{};
    if (tile < ntiles) {
        const float* base = x + (size_t)tile * 4096;
        const float4* pa = (const float4*)(base + (2 * r0) * 64 + chunk * 8);
        const float4* pb = (const float4*)(base + (2 * r0 + 1) * 64 + chunk * 8);
        a0 = pa[0]; a1 = pa[1]; b0 = pb[0]; b1 = pb[1];
    }

    while (tile < ntiles) {
        __syncthreads();  // previous tile's LDS readers done
        // convert + stage current tile (regs already loaded)
        unsigned int ha[8], hb[8];
        ha[0] = f2bf(a0.x); ha[1] = f2bf(a0.y); ha[2] = f2bf(a0.z); ha[3] = f2bf(a0.w);
        ha[4] = f2bf(a1.x); ha[5] = f2bf(a1.y); ha[6] = f2bf(a1.z); ha[7] = f2bf(a1.w);
        hb[0] = f2bf(b0.x); hb[1] = f2bf(b0.y); hb[2] = f2bf(b0.z); hb[3] = f2bf(b0.w);
        hb[4] = f2bf(b1.x); hb[5] = f2bf(b1.y); hb[6] = f2bf(b1.z); hb[7] = f2bf(b1.w);
        unsigned int* dst = sm + r0 * GPADC + chunk * 8;
        *(uint4*)dst = make_uint4(ha[0] | (hb[0] << 16), ha[1] | (hb[1] << 16),
                                  ha[2] | (hb[2] << 16), ha[3] | (hb[3] << 16));
        *(uint4*)(dst + 4) = make_uint4(ha[4] | (hb[4] << 16), ha[5] | (hb[5] << 16),
                                        ha[6] | (hb[6] << 16), ha[7] | (hb[7] << 16));
        __syncthreads();

        // issue next tile's loads (fly under the MFMA phase)
        const int nt = tile + nblk;
        float4 na0 = a0, na1 = a1, nb0 = b0, nb1 = b1;
        if (nt < ntiles) {
            const float* base = x + (size_t)nt * 4096;
            const float4* pa = (const float4*)(base + (2 * r0) * 64 + chunk * 8);
            const float4* pb = (const float4*)(base + (2 * r0 + 1) * 64 + chunk * 8);
            na0 = pa[0]; na1 = pa[1]; nb0 = pb[0]; nb1 = pb[1];
        }

        // MFMA phase on staged LDS
#pragma unroll
        for (int s = 0; s < 2; ++s) {
            short8b fr[4];
#pragma unroll
            for (int c = 0; c < 4; ++c) {
                FragU fu;
#pragma unroll
                for (int h = 0; h < 4; ++h)
                    fu.w[h] = sm[(s * 16 + g * 4 + h) * GPADC + c * 16 + il];
                fr[c] = fu.s;
            }
#pragma unroll
            for (int tj = 0; tj < 4; ++tj)
                acc[tj] = __builtin_amdgcn_mfma_f32_16x16x32_bf16(fr[wv], fr[tj], acc[tj], 0, 0, 0);
            accs = __builtin_amdgcn_mfma_f32_16x16x32_bf16(ones.s, fr[wv], accs, 0, 0, 0);
        }

        tile = nt;
        a0 = na0; a1 = na1; b0 = nb0; b1 = nb1;
    }
    // store partial G: lane holds G[wv*16 + g*4+q][tj*16+il]
    float* part = ws + WS_PART + (size_t)blockIdx.x * PART_STRIDE;
#pragma unroll
    for (int tj = 0; tj < 4; ++tj)
#pragma unroll
        for (int q = 0; q < 4; ++q)
            part[(wv * 16 + g * 4 + q) * 64 + tj * 16 + il] = acc[tj][q];
    if (g == 0) part[4096 + wv * 16 + il] = accs[0];
}

// ---------------- Reduce partials: one wave per element ---------------------
__global__ __launch_bounds__(256) void k_reduce(float* __restrict__ ws, int nba) {
    const int g = blockIdx.x * 4 + (threadIdx.x >> 6);  // grid 1040 -> [0,4160)
    const int lane = threadIdx.x & 63;
    const float* p = ws + WS_PART + g;
    float s = 0.f;
    for (int b = lane; b < nba; b += 64) s += p[(size_t)b * PART_STRIDE];
#pragma unroll
    for (int m = 1; m < 64; m <<= 1) s += __shfl_xor(s, m, 64);
    if (lane == 0) ws[g] = s;
}

// ---------------- Finalize BN stats + pack W fragments ----------------------
__global__ __launch_bounds__(256) void k_finalize(const float* __restrict__ w,
                                                  const float* __restrict__ gamma,
                                                  const float* __restrict__ beta,
                                                  float* __restrict__ ws) {
    __shared__ float Gs[4096];
    __shared__ float ssum[64];
    __shared__ float red1[256], red2[256];
    const int t = threadIdx.x;

    // folded k_prepw: pack W into MFMA B-fragment layout (bf16)
    {
        uint4* dst = (uint4*)(ws + WS_WFRAG);
#pragma unroll
        for (int ii = 0; ii < 4; ++ii) {
            const int tt = ii * 256 + t;  // 0..1023
            const int l = tt & 63;
            const int s = (tt >> 6) & 1;
            const int c = tt >> 7;
            const int col = c * 16 + (l & 15);
            const int kk = col >> 5, o = col & 31;
            unsigned int pk[4];
#pragma unroll
            for (int jj = 0; jj < 4; ++jj) {
                const int k0 = s * 32 + ((l >> 4) << 3) + jj * 2;
                unsigned int b0 = f2bf(w[(kk * 64 + k0) * 32 + o]);
                unsigned int b1 = f2bf(w[(kk * 64 + k0 + 1) * 32 + o]);
                pk[jj] = b0 | (b1 << 16);
            }
            dst[tt] = make_uint4(pk[0], pk[1], pk[2], pk[3]);
        }
    }

    for (int i = t; i < 4096; i += 256) Gs[i] = ws[i];
    if (t < 64) ssum[t] = ws[WS_S + t];
    __syncthreads();
    const int sub = t >> 7;
    const int k = (t >> 5) & 3;
    const int o = t & 31;
    float wc[64];
#pragma unroll
    for (int i = 0; i < 64; ++i) wc[i] = w[(k * 64 + i) * 32 + o];
    float m1 = 0.f, m2 = 0.f;
    for (int ii = 0; ii < 32; ++ii) {
        int i = sub * 32 + ii;
        m1 = fmaf(ssum[i], wc[i], m1);
        float ti = 0.f;
#pragma unroll
        for (int j = 0; j < 64; ++j) ti = fmaf(Gs[i * 64 + j], wc[j], ti);
        m2 = fmaf(wc[i], ti, m2);
    }
    red1[t] = m1;
    red2[t] = m2;
    __syncthreads();
    if (t < 32) {
        float s1 = 0.f, s2 = 0.f;
#pragma unroll
        for (int q = 0; q < 8; ++q) {
            int idx = (q & 3) * 32 + (q >> 2) * 128 + t;
            s1 += red1[idx];
            s2 += red2[idx];
        }
        float inv = 1.f / (float)NTOT;
        float mean = s1 * inv;
        float var = s2 * inv - mean * mean;
        float rstd = rsqrtf(var + BN_EPS);
        float sc = gamma[t] * rstd;
        ws[WS_SCALE + t] = sc;
        ws[WS_BIAS + t] = beta[t] - mean * sc;
    }
}

// ---------------- Main: MFMA GEMM + BN + ReLU + coalesced scatter (R8) ------
// Forward order. W fragments from global (L1-resident 16KB). 4 blocks/CU.
// Epilogue: chunk-XOR-swizzled LDS transpose + 8-lanes-per-row stores
// (each store instruction writes 8 FULL 128B lines). This kernel sits at
// ~92% of the random-128B-line DRAM write wall (~2 TB/s) — proven by the
// R7/R10/R11/R12 experiment family; do not re-attempt gather/NT/bf16 reads.
__global__ __launch_bounds__(256, 4) void k_main(const float* __restrict__ x,
                                                 const int* __restrict__ oidx,
                                                 const float* __restrict__ ws,
                                                 float* __restrict__ out) {
    __shared__ float ldsD[4][64 * 32];
    __shared__ int ldsO[4][64];
    const int t = threadIdx.x, wv = t >> 6, l = t & 63;
    const int il = l & 15, g = l >> 4;
    const int c8 = l & 7, g8 = l >> 3;

    const float sc0 = ws[WS_SCALE + il], sc1 = ws[WS_SCALE + 16 + il];
    const float bs0 = ws[WS_BIAS + il], bs1 = ws[WS_BIAS + 16 + il];
    const short8b* wfs = (const short8b*)(ws + WS_WFRAG);

    float* myD = ldsD[wv];
    int* myO = ldsO[wv];

    const int wgid = blockIdx.x * 4 + wv;  // 0..7499
    int rowbase = wgid * 80;               // 5 tiles x 16 rows

    float4 cur0, cur1, cur2, cur3;
    {
        const float4* ap = (const float4*)(x + (size_t)(rowbase + il) * 64 + g * 8);
        cur0 = ap[0]; cur1 = ap[1]; cur2 = ap[8]; cur3 = ap[9];
    }
    int orow_cur = oidx[g * N_IN + rowbase + il];

#pragma unroll
    for (int it = 0; it < 5; ++it) {
        myO[l] = orow_cur;

        FragU af0, af1;
        af0.w[0] = (unsigned)f2bf(cur0.x) | ((unsigned)f2bf(cur0.y) << 16);
        af0.w[1] = (unsigned)f2bf(cur0.z) | ((unsigned)f2bf(cur0.w) << 16);
        af0.w[2] = (unsigned)f2bf(cur1.x) | ((unsigned)f2bf(cur1.y) << 16);
        af0.w[3] = (unsigned)f2bf(cur1.z) | ((unsigned)f2bf(cur1.w) << 16);
        af1.w[0] = (unsigned)f2bf(cur2.x) | ((unsigned)f2bf(cur2.y) << 16);
        af1.w[1] = (unsigned)f2bf(cur2.z) | ((unsigned)f2bf(cur2.w) << 16);
        af1.w[2] = (unsigned)f2bf(cur3.x) | ((unsigned)f2bf(cur3.y) << 16);
        af1.w[3] = (unsigned)f2bf(cur3.z) | ((unsigned)f2bf(cur3.w) << 16);

        float4 nx0{}, nx1{}, nx2{}, nx3{};
        int orow_nxt = 0;
        if (it < 4) {
            const float4* ap = (const float4*)(x + (size_t)(rowbase + 16 + il) * 64 + g * 8);
            nx0 = ap[0]; nx1 = ap[1]; nx2 = ap[8]; nx3 = ap[9];
            orow_nxt = oidx[g * N_IN + rowbase + 16 + il];
        }

        f32x4 acc[8];
#pragma unroll
        for (int c = 0; c < 8; ++c) acc[c] = (f32x4){0.f, 0.f, 0.f, 0.f};
#pragma unroll
        for (int c = 0; c < 8; ++c)
            acc[c] = __builtin_amdgcn_mfma_f32_16x16x32_bf16(af0.s, wfs[(c * 2 + 0) * 64 + l], acc[c], 0, 0, 0);
#pragma unroll
        for (int c = 0; c < 8; ++c)
            acc[c] = __builtin_amdgcn_mfma_f32_16x16x32_bf16(af1.s, wfs[(c * 2 + 1) * 64 + l], acc[c], 0, 0, 0);

#pragma unroll
        for (int c = 0; c < 8; ++c) {
            const float sc = (c & 1) ? sc1 : sc0;
            const float bs = (c & 1) ? bs1 : bs0;
            const int ch = (c & 1) * 16 + il;
            const int cc = ch >> 2, wd = ch & 3;
            const int rb = (c >> 1) * 16 + g * 4;
#pragma unroll
            for (int q = 0; q < 4; ++q) {
                const int R = rb + q;
                const float v = fmaxf(0.f, fmaf(acc[c][q], sc, bs));
                myD[R * 32 + (((cc ^ (R & 7)) << 2) | wd)] = v;
            }
        }
#pragma unroll
        for (int m = 0; m < 8; ++m) {
            const int R = m * 8 + g8;
            const float4 v = *(const float4*)(myD + R * 32 + ((c8 ^ g8) << 2));
            const int orow = myO[R];
            *(float4*)(out + (size_t)orow * 32 + c8 * 4) = v;
        }

        rowbase += 16;
        cur0 = nx0; cur1 = nx1; cur2 = nx2; cur3 = nx3;
        orow_cur = orow_nxt;
    }
}

extern "C" void kernel_launch(void* const* d_in, const int* in_sizes, int n_in,
                              void* d_out, int out_size, void* d_ws, size_t ws_size,
                              hipStream_t stream) {
    const float* x = (const float*)d_in[0];
    const float* w = (const float*)d_in[1];
    const float* gamma = (const float*)d_in[2];
    const float* beta = (const float*)d_in[3];
    const int* oidx = (const int*)d_in[4];
    float* out = (float*)d_out;
    float* ws = (float*)d_ws;

    int nba = NBA;
    size_t cap = ws_size / sizeof(float);
    if (cap < (size_t)WS_PART + (size_t)nba * PART_STRIDE) {
        size_t fit = (cap - WS_PART) / PART_STRIDE;
        nba = (int)(fit < 1 ? 1 : fit);
        if (nba > NBA) nba = NBA;
    }

    hipLaunchKernelGGL(k_gram, dim3(nba), dim3(256), 0, stream, x, ws, nba);
    hipLaunchKernelGGL(k_reduce, dim3(1040), dim3(256), 0, stream, ws, nba);
    hipLaunchKernelGGL(k_finalize, dim3(1), dim3(256), 0, stream, w, gamma, beta, ws);
    hipLaunchKernelGGL(k_main, dim3(1875), dim3(256), 0, stream, x, oidx, ws, out);
}

// Round 14
// 219.238 us; speedup vs baseline: 1.9430x; 1.2510x over previous
//
#include <hip/hip_runtime.h>

#define N_IN 600000
#define KK 4
#define C_IN 64
#define C_OUT 32
#define NTOT (KK*N_IN)
#define BN_EPS 1e-5f

typedef __attribute__((ext_vector_type(8))) short short8b;   // 8 bf16 (4 VGPRs)
typedef __attribute__((ext_vector_type(4))) float f32x4;     // MFMA C/D

// ws float layout:
// [0,4096)      G (64x64 Gram, final)
// [4096,4160)   s (colsum, final)
// [4160,4192)   scale[32]
// [4192,4224)   bias[32]
// [4224,8320)   W bf16 fragments (1024 uint4 = 16KB)
// [8320, +512*4160)  per-block gram partials
#define WS_G 0
#define WS_S 4096
#define WS_SCALE 4160
#define WS_BIAS 4192
#define WS_WFRAG 4224
#define WS_PART 8320
#define PART_STRIDE 4160
#define NBA 512

__device__ __forceinline__ unsigned short f2bf(float f) {
    unsigned int u = __float_as_uint(f);
    u += 0x7fffu + ((u >> 16) & 1u);   // RNE
    return (unsigned short)(u >> 16);
}

union FragU { uint4 u; short8b s; unsigned int w[4]; };

// ---------------- Pass A: Gram G = X^T X + colsums, via MFMA ----------------
// Stage 64x64 tile in LDS as PRE-PACKED bf16 k-pairs (exactly the MFMA
// fragment dword format): fragment read = 4 scalar b32 (2-way bank = free),
// zero repack VALU. Same fragment serves as A and B. NOTE (R13): do NOT
// software-pipeline this loop — loads issued before the first barrier let
// the barrier straggler-wait absorb HBM latency; explicit pipelining
// regressed 45us.
#define GPADC 68
__global__ __launch_bounds__(256) void k_gram(const float* __restrict__ x,
                                              float* __restrict__ ws, int nblk) {
    __shared__ unsigned int sm[32 * GPADC];  // 32 row-pairs x 64 packed cols (+pad)
    const int t = threadIdx.x, wv = t >> 6, l = t & 63;
    const int il = l & 15, g = l >> 4;
    const int chunk = t & 7, r0 = t >> 3;

    FragU ones;
    ones.u = make_uint4(0x3f803f80u, 0x3f803f80u, 0x3f803f80u, 0x3f803f80u);

    f32x4 acc[4];
    f32x4 accs = (f32x4){0.f, 0.f, 0.f, 0.f};
#pragma unroll
    for (int j = 0; j < 4; ++j) acc[j] = (f32x4){0.f, 0.f, 0.f, 0.f};

    const int ntiles = N_IN / 64;  // 9375
    for (int tile = blockIdx.x; tile < ntiles; tile += nblk) {
        const float* base = x + (size_t)tile * 4096;
        const float4* pa = (const float4*)(base + (2 * r0) * 64 + chunk * 8);
        const float4* pb = (const float4*)(base + (2 * r0 + 1) * 64 + chunk * 8);
        const float4 a0 = pa[0], a1 = pa[1];
        const float4 b0 = pb[0], b1 = pb[1];
        __syncthreads();
        unsigned int pk[8];
        pk[0] = (unsigned)f2bf(a0.x) | ((unsigned)f2bf(b0.x) << 16);
        pk[1] = (unsigned)f2bf(a0.y) | ((unsigned)f2bf(b0.y) << 16);
        pk[2] = (unsigned)f2bf(a0.z) | ((unsigned)f2bf(b0.z) << 16);
        pk[3] = (unsigned)f2bf(a0.w) | ((unsigned)f2bf(b0.w) << 16);
        pk[4] = (unsigned)f2bf(a1.x) | ((unsigned)f2bf(b1.x) << 16);
        pk[5] = (unsigned)f2bf(a1.y) | ((unsigned)f2bf(b1.y) << 16);
        pk[6] = (unsigned)f2bf(a1.z) | ((unsigned)f2bf(b1.z) << 16);
        pk[7] = (unsigned)f2bf(a1.w) | ((unsigned)f2bf(b1.w) << 16);
        unsigned int* dst = sm + r0 * GPADC + chunk * 8;
        *(uint4*)dst = make_uint4(pk[0], pk[1], pk[2], pk[3]);
        *(uint4*)(dst + 4) = make_uint4(pk[4], pk[5], pk[6], pk[7]);
        __syncthreads();
#pragma unroll
        for (int s = 0; s < 2; ++s) {
            short8b fr[4];
#pragma unroll
            for (int c = 0; c < 4; ++c) {
                FragU fu;
#pragma unroll
                for (int h = 0; h < 4; ++h)
                    fu.w[h] = sm[(s * 16 + g * 4 + h) * GPADC + c * 16 + il];
                fr[c] = fu.s;
            }
#pragma unroll
            for (int tj = 0; tj < 4; ++tj)
                acc[tj] = __builtin_amdgcn_mfma_f32_16x16x32_bf16(fr[wv], fr[tj], acc[tj], 0, 0, 0);
            accs = __builtin_amdgcn_mfma_f32_16x16x32_bf16(ones.s, fr[wv], accs, 0, 0, 0);
        }
    }
    float* part = ws + WS_PART + (size_t)blockIdx.x * PART_STRIDE;
#pragma unroll
    for (int tj = 0; tj < 4; ++tj)
#pragma unroll
        for (int q = 0; q < 4; ++q)
            part[(wv * 16 + g * 4 + q) * 64 + tj * 16 + il] = acc[tj][q];
    if (g == 0) part[4096 + wv * 16 + il] = accs[0];
}

// ---------------- Reduce partials: one wave per element ---------------------
__global__ __launch_bounds__(256) void k_reduce(float* __restrict__ ws, int nba) {
    const int g = blockIdx.x * 4 + (threadIdx.x >> 6);  // grid 1040 -> [0,4160)
    const int lane = threadIdx.x & 63;
    const float* p = ws + WS_PART + g;
    float s = 0.f;
    for (int b = lane; b < nba; b += 64) s += p[(size_t)b * PART_STRIDE];
#pragma unroll
    for (int m = 1; m < 64; m <<= 1) s += __shfl_xor(s, m, 64);
    if (lane == 0) ws[g] = s;
}

// ---------------- Finalize BN stats + pack W fragments ----------------------
__global__ __launch_bounds__(256) void k_finalize(const float* __restrict__ w,
                                                  const float* __restrict__ gamma,
                                                  const float* __restrict__ beta,
                                                  float* __restrict__ ws) {
    __shared__ float Gs[4096];
    __shared__ float ssum[64];
    __shared__ float red1[256], red2[256];
    const int t = threadIdx.x;

    // ---- folded k_prepw: pack W into MFMA B-fragment layout (bf16) ----
    {
        uint4* dst = (uint4*)(ws + WS_WFRAG);
#pragma unroll
        for (int ii = 0; ii < 4; ++ii) {
            const int tt = ii * 256 + t;  // 0..1023
            const int l = tt & 63;
            const int s = (tt >> 6) & 1;
            const int c = tt >> 7;
            const int col = c * 16 + (l & 15);
            const int kk = col >> 5, o = col & 31;
            unsigned int pk[4];
#pragma unroll
            for (int jj = 0; jj < 4; ++jj) {
                const int k0 = s * 32 + ((l >> 4) << 3) + jj * 2;
                unsigned int b0 = f2bf(w[(kk * 64 + k0) * 32 + o]);
                unsigned int b1 = f2bf(w[(kk * 64 + k0 + 1) * 32 + o]);
                pk[jj] = b0 | (b1 << 16);
            }
            dst[tt] = make_uint4(pk[0], pk[1], pk[2], pk[3]);
        }
    }

    for (int i = t; i < 4096; i += 256) Gs[i] = ws[i];
    if (t < 64) ssum[t] = ws[WS_S + t];
    __syncthreads();
    const int sub = t >> 7;
    const int k = (t >> 5) & 3;
    const int o = t & 31;
    float wc[64];
#pragma unroll
    for (int i = 0; i < 64; ++i) wc[i] = w[(k * 64 + i) * 32 + o];
    float m1 = 0.f, m2 = 0.f;
    for (int ii = 0; ii < 32; ++ii) {
        int i = sub * 32 + ii;
        m1 = fmaf(ssum[i], wc[i], m1);
        float ti = 0.f;
#pragma unroll
        for (int j = 0; j < 64; ++j) ti = fmaf(Gs[i * 64 + j], wc[j], ti);
        m2 = fmaf(wc[i], ti, m2);
    }
    red1[t] = m1;
    red2[t] = m2;
    __syncthreads();
    if (t < 32) {
        float s1 = 0.f, s2 = 0.f;
#pragma unroll
        for (int q = 0; q < 8; ++q) {
            int idx = (q & 3) * 32 + (q >> 2) * 128 + t;
            s1 += red1[idx];
            s2 += red2[idx];
        }
        float inv = 1.f / (float)NTOT;
        float mean = s1 * inv;
        float var = s2 * inv - mean * mean;
        float rstd = rsqrtf(var + BN_EPS);
        float sc = gamma[t] * rstd;
        ws[WS_SCALE + t] = sc;
        ws[WS_BIAS + t] = beta[t] - mean * sc;
    }
}

// ---------------- Main: MFMA GEMM + BN + ReLU + coalesced scatter -----------
// 1875 blocks x 4 waves x 5 tiles = 37500 tiles. W fragments read per tile
// from global (L1-resident 16KB; VGPR-hoisting never sticks — R3/R7).
// launch_bounds(256,4): 16 waves/CU for max scatter-write MLP.
// Epilogue: chunk-XOR-swizzled LDS transpose, then 8-lanes-per-row stores
// (each store instruction writes 8 FULL 128B lines). Sits at ~92% of the
// random-128B-line DRAM write wall (~2 TB/s) — proven by the R7/R10/R11/R12
// family; do not re-attempt gather/NT/bf16-read variants.
__global__ __launch_bounds__(256, 4) void k_main(const float* __restrict__ x,
                                                 const int* __restrict__ oidx,
                                                 const float* __restrict__ ws,
                                                 float* __restrict__ out) {
    __shared__ float ldsD[4][64 * 32];
    __shared__ int ldsO[4][64];
    const int t = threadIdx.x, wv = t >> 6, l = t & 63;
    const int il = l & 15, g = l >> 4;
    const int c8 = l & 7, g8 = l >> 3;

    const float sc0 = ws[WS_SCALE + il], sc1 = ws[WS_SCALE + 16 + il];
    const float bs0 = ws[WS_BIAS + il], bs1 = ws[WS_BIAS + 16 + il];
    const short8b* wfs = (const short8b*)(ws + WS_WFRAG);

    float* myD = ldsD[wv];
    int* myO = ldsO[wv];

    const int wgid = blockIdx.x * 4 + wv;  // 0..7499
    int rowbase = wgid * 80;               // 5 tiles x 16 rows

    // prefetch tile 0
    float4 cur0, cur1, cur2, cur3;
    {
        const float4* ap = (const float4*)(x + (size_t)(rowbase + il) * 64 + g * 8);
        cur0 = ap[0]; cur1 = ap[1]; cur2 = ap[8]; cur3 = ap[9];
    }
    int orow_cur = oidx[g * N_IN + rowbase + il];

#pragma unroll
    for (int it = 0; it < 5; ++it) {
        myO[l] = orow_cur;  // stage this tile's 64 scatter rows (local row l)

        FragU af0, af1;
        af0.w[0] = (unsigned)f2bf(cur0.x) | ((unsigned)f2bf(cur0.y) << 16);
        af0.w[1] = (unsigned)f2bf(cur0.z) | ((unsigned)f2bf(cur0.w) << 16);
        af0.w[2] = (unsigned)f2bf(cur1.x) | ((unsigned)f2bf(cur1.y) << 16);
        af0.w[3] = (unsigned)f2bf(cur1.z) | ((unsigned)f2bf(cur1.w) << 16);
        af1.w[0] = (unsigned)f2bf(cur2.x) | ((unsigned)f2bf(cur2.y) << 16);
        af1.w[1] = (unsigned)f2bf(cur2.z) | ((unsigned)f2bf(cur2.w) << 16);
        af1.w[2] = (unsigned)f2bf(cur3.x) | ((unsigned)f2bf(cur3.y) << 16);
        af1.w[3] = (unsigned)f2bf(cur3.z) | ((unsigned)f2bf(cur3.w) << 16);

        // prefetch next tile (overlaps MFMA + epilogue)
        float4 nx0{}, nx1{}, nx2{}, nx3{};
        int orow_nxt = 0;
        if (it < 4) {
            const float4* ap = (const float4*)(x + (size_t)(rowbase + 16 + il) * 64 + g * 8);
            nx0 = ap[0]; nx1 = ap[1]; nx2 = ap[8]; nx3 = ap[9];
            orow_nxt = oidx[g * N_IN + rowbase + 16 + il];
        }

        f32x4 acc[8];
#pragma unroll
        for (int c = 0; c < 8; ++c) acc[c] = (f32x4){0.f, 0.f, 0.f, 0.f};
#pragma unroll
        for (int c = 0; c < 8; ++c)
            acc[c] = __builtin_amdgcn_mfma_f32_16x16x32_bf16(af0.s, wfs[(c * 2 + 0) * 64 + l], acc[c], 0, 0, 0);
#pragma unroll
        for (int c = 0; c < 8; ++c)
            acc[c] = __builtin_amdgcn_mfma_f32_16x16x32_bf16(af1.s, wfs[(c * 2 + 1) * 64 + l], acc[c], 0, 0, 0);

        // BN + ReLU -> swizzled LDS: phys dword = R*32 + ((cc ^ (R&7))<<2) + wd
#pragma unroll
        for (int c = 0; c < 8; ++c) {
            const float sc = (c & 1) ? sc1 : sc0;
            const float bs = (c & 1) ? bs1 : bs0;
            const int ch = (c & 1) * 16 + il;
            const int cc = ch >> 2, wd = ch & 3;
            const int rb = (c >> 1) * 16 + g * 4;
#pragma unroll
            for (int q = 0; q < 4; ++q) {
                const int R = rb + q;
                const float v = fmaxf(0.f, fmaf(acc[c][q], sc, bs));
                myD[R * 32 + (((cc ^ (R & 7)) << 2) | wd)] = v;
            }
        }
        // stores: lane group g8 owns row R=m*8+g8, chunk c8; R&7==g8 always
#pragma unroll
        for (int m = 0; m < 8; ++m) {
            const int R = m * 8 + g8;
            const float4 v = *(const float4*)(myD + R * 32 + ((c8 ^ g8) << 2));
            const int orow = myO[R];
            *(float4*)(out + (size_t)orow * 32 + c8 * 4) = v;
        }

        rowbase += 16;
        cur0 = nx0; cur1 = nx1; cur2 = nx2; cur3 = nx3;
        orow_cur = orow_nxt;
    }
}

extern "C" void kernel_launch(void* const* d_in, const int* in_sizes, int n_in,
                              void* d_out, int out_size, void* d_ws, size_t ws_size,
                              hipStream_t stream) {
    const float* x = (const float*)d_in[0];
    const float* w = (const float*)d_in[1];
    const float* gamma = (const float*)d_in[2];
    const float* beta = (const float*)d_in[3];
    const int* oidx = (const int*)d_in[4];
    float* out = (float*)d_out;
    float* ws = (float*)d_ws;

    int nba = NBA;
    size_t cap = ws_size / sizeof(float);
    if (cap < (size_t)WS_PART + (size_t)nba * PART_STRIDE) {
        size_t fit = (cap - WS_PART) / PART_STRIDE;
        nba = (int)(fit < 1 ? 1 : fit);
        if (nba > NBA) nba = NBA;
    }

    hipLaunchKernelGGL(k_gram, dim3(nba), dim3(256), 0, stream, x, ws, nba);
    hipLaunchKernelGGL(k_reduce, dim3(1040), dim3(256), 0, stream, ws, nba);
    hipLaunchKernelGGL(k_finalize, dim3(1), dim3(256), 0, stream, w, gamma, beta, ws);
    hipLaunchKernelGGL(k_main, dim3(1875), dim3(256), 0, stream, x, oidx, ws, out);
}